// Round 3
// baseline (1031.313 us; speedup 1.0000x reference)
//
#include <hip/hip_runtime.h>

// PowerSpectrum: out[n, l*4096 + f*64 + g] = (2l+1)^{-1/2} * sum_m c_l[n,m,f]*c_l[n,m,g]
// N=10000 samples, NF=64, l=0..5 (m sizes 1,3,5,7,9,11; total 36 m-rows, 2304 floats/sample)
//
// Memory-bound (write-dominated): 983 MB out + 92 MB in => floor ~170us @ 6.3 TB/s.
// One block per sample: stage c_l[n] rows in LDS (9.2 KB), each thread computes a
// 4x4 tile of each 64x64 Gram matrix, nontemporal float4 stores (write-once stream).

#define NF 64
#define NL 6

// native clang vector type: __builtin_nontemporal_* requires it (HIP float4 is a class)
typedef float f4 __attribute__((ext_vector_type(4)));

__constant__ float CG[NL] = {
    1.0f,                 // 1/sqrt(1)
    0.57735026918962576f, // 1/sqrt(3)
    0.44721359549995794f, // 1/sqrt(5)
    0.37796447300922722f, // 1/sqrt(7)
    0.33333333333333333f, // 1/sqrt(9)
    0.30151134457776363f  // 1/sqrt(11)
};

__global__ __launch_bounds__(256, 2) void ps_kernel(
    const float* __restrict__ c0, const float* __restrict__ c1,
    const float* __restrict__ c2, const float* __restrict__ c3,
    const float* __restrict__ c4, const float* __restrict__ c5,
    float* __restrict__ out)
{
    // LDS: concat of all 6 c_l[n] blocks; offset of block l is l*l*64 floats
    // (sum of (2k+1) for k<l = l^2). Total 36*64 = 2304 floats = 9216 B.
    __shared__ float lds[2304];

    const float* cs[NL] = {c0, c1, c2, c3, c4, c5};
    const int n = blockIdx.x;
    const int tid = threadIdx.x;

    // ---- stage: coalesced float4 global->LDS, each input byte read once ----
#pragma unroll
    for (int l = 0; l < NL; ++l) {
        const int nm = 2 * l + 1;
        const f4* src = (const f4*)(cs[l] + (size_t)n * (nm * NF));
        f4* dst = (f4*)(lds + l * l * NF);
        const int cnt4 = nm * (NF / 4);
        for (int i = tid; i < cnt4; i += 256)
            dst[i] = __builtin_nontemporal_load(&src[i]);
    }
    __syncthreads();

    // ---- compute: thread owns rows f0..f0+3, cols g4..g4+3 of each 64x64 tile
    // lanes 0..15 share f0 (a-read broadcasts); g4 walks 0..60 (b-read 2-way, free).
    // Store: each 16-lane group writes one contiguous 256B row chunk.
    const int f0 = ((tid >> 4) << 2); // 0,4,8,...,60 per 16-lane group
    const int g4 = ((tid & 15) << 2); // 0,4,...,60 within group

    float* outn = out + (size_t)n * (NL * NF * NF);

#pragma unroll
    for (int l = 0; l < NL; ++l) {
        const int nm = 2 * l + 1;
        const float* cl = lds + l * l * NF;
        const float cg = CG[l];

        f4 acc[4];
#pragma unroll
        for (int r = 0; r < 4; ++r) acc[r] = (f4)(0.f);

        for (int m = 0; m < nm; ++m) {
            const float* row = cl + m * NF;
            const f4 a = *(const f4*)(row + f0); // broadcast within 16 lanes
            const f4 b = *(const f4*)(row + g4); // spans banks, 2-way max
#pragma unroll
            for (int r = 0; r < 4; ++r) {
                acc[r] += a[r] * b;
            }
        }

        float* po = outn + l * (NF * NF);
#pragma unroll
        for (int r = 0; r < 4; ++r) {
            f4 v = acc[r] * cg;
            __builtin_nontemporal_store(v, (f4*)(po + (size_t)(f0 + r) * NF + g4));
        }
    }
}

extern "C" void kernel_launch(void* const* d_in, const int* in_sizes, int n_in,
                              void* d_out, int out_size, void* d_ws, size_t ws_size,
                              hipStream_t stream) {
    const float* c0 = (const float*)d_in[0];
    const float* c1 = (const float*)d_in[1];
    const float* c2 = (const float*)d_in[2];
    const float* c3 = (const float*)d_in[3];
    const float* c4 = (const float*)d_in[4];
    const float* c5 = (const float*)d_in[5];
    float* outp = (float*)d_out;

    const int N = in_sizes[0] / NF; // c0 is (N, 1, 64)

    hipLaunchKernelGGL(ps_kernel, dim3(N), dim3(256), 0, stream,
                       c0, c1, c2, c3, c4, c5, outp);
}

// Round 6
// 1024.316 us; speedup vs baseline: 1.0068x; 1.0068x over previous
//
#include <hip/hip_runtime.h>

// PowerSpectrum: out[n, l*4096 + f*64 + g] = (2l+1)^{-1/2} * sum_m c_l[n,m,f]*c_l[n,m,g]
// N=10000 samples, NF=64, l=0..5 (m sizes 1,3,5,7,9,11; 36 m-rows, 2304 floats/sample)
//
// Write-dominated: 983 MB out + 92 MB in => floor ~170us @ 6.3 TB/s.
// One block per sample; stage c[n] in LDS; thread computes 4x4 tile per l; float4 stores.
// This round: 4 blocks/CU (was 2) for deeper store pipelining, and an NT-vs-regular
// store A/B split across two dispatches (samples [0,N/2) NT, [N/2,N) regular).

#define NF 64
#define NL 6

typedef float f4 __attribute__((ext_vector_type(4)));

__constant__ float CG[NL] = {
    1.0f,                 // 1/sqrt(1)
    0.57735026918962576f, // 1/sqrt(3)
    0.44721359549995794f, // 1/sqrt(5)
    0.37796447300922722f, // 1/sqrt(7)
    0.33333333333333333f, // 1/sqrt(9)
    0.30151134457776363f  // 1/sqrt(11)
};

template <bool NT>
__global__ __launch_bounds__(256, 4) void ps_kernel(
    const float* __restrict__ c0, const float* __restrict__ c1,
    const float* __restrict__ c2, const float* __restrict__ c3,
    const float* __restrict__ c4, const float* __restrict__ c5,
    float* __restrict__ out, int n_base)
{
    __shared__ float lds[2304]; // block l at offset l*l*64 (sum of 2k+1, k<l = l^2)

    const float* cs[NL] = {c0, c1, c2, c3, c4, c5};
    const int n = n_base + blockIdx.x;
    const int tid = threadIdx.x;

    // ---- stage: coalesced float4 global->LDS, each input byte read once ----
#pragma unroll
    for (int l = 0; l < NL; ++l) {
        const int nm = 2 * l + 1;
        const f4* src = (const f4*)(cs[l] + (size_t)n * (nm * NF));
        f4* dst = (f4*)(lds + l * l * NF);
        const int cnt4 = nm * (NF / 4);
        for (int i = tid; i < cnt4; i += 256)
            dst[i] = __builtin_nontemporal_load(&src[i]);
    }
    __syncthreads();

    // thread owns rows f0..f0+3, cols g4..g4+3 of each 64x64 Gram tile
    const int f0 = ((tid >> 4) << 2);
    const int g4 = ((tid & 15) << 2);

    float* outn = out + (size_t)n * (NL * NF * NF);

#pragma unroll
    for (int l = 0; l < NL; ++l) {
        const int nm = 2 * l + 1;
        const float* cl = lds + l * l * NF;
        const float cg = CG[l];

        f4 acc[4];
#pragma unroll
        for (int r = 0; r < 4; ++r) acc[r] = (f4)(0.f);

        for (int m = 0; m < nm; ++m) {
            const float* row = cl + m * NF;
            const f4 a = *(const f4*)(row + f0); // 16-lane broadcast
            const f4 b = *(const f4*)(row + g4); // 2-way max (free)
#pragma unroll
            for (int r = 0; r < 4; ++r) acc[r] += a[r] * b;
        }

        float* po = outn + l * (NF * NF);
#pragma unroll
        for (int r = 0; r < 4; ++r) {
            f4 v = acc[r] * cg;
            f4* dst = (f4*)(po + (size_t)(f0 + r) * NF + g4);
            if constexpr (NT) __builtin_nontemporal_store(v, dst);
            else              *dst = v;
        }
    }
}

extern "C" void kernel_launch(void* const* d_in, const int* in_sizes, int n_in,
                              void* d_out, int out_size, void* d_ws, size_t ws_size,
                              hipStream_t stream) {
    const float* c0 = (const float*)d_in[0];
    const float* c1 = (const float*)d_in[1];
    const float* c2 = (const float*)d_in[2];
    const float* c3 = (const float*)d_in[3];
    const float* c4 = (const float*)d_in[4];
    const float* c5 = (const float*)d_in[5];
    float* outp = (float*)d_out;

    const int N = in_sizes[0] / NF; // c0 is (N, 1, 64)
    const int Nh = N / 2;

    // A/B: first half NT stores, second half regular stores (identical math).
    hipLaunchKernelGGL(ps_kernel<true>, dim3(Nh), dim3(256), 0, stream,
                       c0, c1, c2, c3, c4, c5, outp, 0);
    hipLaunchKernelGGL(ps_kernel<false>, dim3(N - Nh), dim3(256), 0, stream,
                       c0, c1, c2, c3, c4, c5, outp, Nh);
}